// Round 9
// baseline (3127.473 us; speedup 1.0000x reference)
//
#include <hip/hip_runtime.h>
#include <math.h>

#define NN 50000
#define NE 800000
#define FIN 197
#define KIN 224          // FIN zero-padded to multiple of 32
#define H 256
#define HEADS 8
#define HD 32
#define LAYERS 5
#define FF 1024
#define INV_SCALE 0.17677669529663687f   // 1/sqrt(32)

typedef __attribute__((ext_vector_type(8))) short short8;
typedef __attribute__((ext_vector_type(4))) float f32x4;
typedef unsigned short ushort;

// fast GELU via exp2/rcp (max abs err ~3e-4 vs exact erf form)
__device__ __forceinline__ float gelu_f(float x) {
    float x2 = x * x;
    float u = __builtin_fmaf(0.044715f * x2, x, x);
    float e = __builtin_amdgcn_exp2f(-2.3022075f * u);
    return x * __builtin_amdgcn_rcpf(1.0f + e);
}
__device__ __forceinline__ ushort f2b(float f) {        // fp32 -> bf16 RNE
    unsigned u = __float_as_uint(f);
    u += 0x7fffu + ((u >> 16) & 1u);
    return (ushort)(u >> 16);
}
__device__ __forceinline__ float b2f(ushort b) {
    return __uint_as_float(((unsigned)b) << 16);
}
__device__ __forceinline__ float dot2b(unsigned a, unsigned b) {  // 2 packed bf16 pairs
    float a0 = __uint_as_float(a << 16), a1 = __uint_as_float(a & 0xffff0000u);
    float b0 = __uint_as_float(b << 16), b1 = __uint_as_float(b & 0xffff0000u);
    return a0 * b0 + a1 * b1;
}

// ---------------- MFMA bf16 GEMM: C = act(A @ Bt^T + bias) + res ----------------
// Pure-bf16-output path (Cb && !Cf) uses an LDS-bounce epilogue: acc -> LDS
// (row stride 132 ushorts: 2-bank shift/row, max 2-way conflict = free) ->
// dwordx4 stores in 256B-contiguous segments. 32B-segment ushort scatter was
// the round-8 bottleneck (MfmaUtil 7.5%, VALUBusy 18%, nothing busy).
#define LDSP 40
#define BP 132
__global__ __launch_bounds__(256) void gemm_bf16_kernel(
    const ushort* __restrict__ A, int lda,
    const ushort* __restrict__ Bt,
    const float* __restrict__ bias,
    const float* __restrict__ res, int ldr,
    float* __restrict__ Cf, ushort* __restrict__ Cb, int ldc,
    int n, int K, int act)
{
    __shared__ ushort lds[2 * 128 * LDSP];
    ushort* As = lds;
    ushort* Bs = lds + 128 * LDSP;
    int tid = threadIdx.x;
    int lane = tid & 63;
    int wave = tid >> 6;
    int wr = wave >> 1, wc = wave & 1;
    int brow = blockIdx.y * 128;
    int bcol = blockIdx.x * 128;

    f32x4 acc[4][4] = {};
    int m0 = lane & 15;
    int koff = (lane >> 4) * 8;

    for (int k0 = 0; k0 < K; k0 += 32) {
        #pragma unroll
        for (int p = 0; p < 2; ++p) {
            int chunk = tid + p * 256;
            int row = chunk >> 2;
            int col8 = (chunk & 3) * 8;
            int gr = brow + row; if (gr >= n) gr = n - 1;
            *(uint4*)&As[row * LDSP + col8] = *(const uint4*)&A[(long)gr * lda + k0 + col8];
            *(uint4*)&Bs[row * LDSP + col8] = *(const uint4*)&Bt[(long)(bcol + row) * K + k0 + col8];
        }
        __syncthreads();
        short8 af[4], bfr[4];
        #pragma unroll
        for (int i = 0; i < 4; ++i)
            af[i] = *(const short8*)&As[(wr * 64 + i * 16 + m0) * LDSP + koff];
        #pragma unroll
        for (int j = 0; j < 4; ++j)
            bfr[j] = *(const short8*)&Bs[(wc * 64 + j * 16 + m0) * LDSP + koff];
        #pragma unroll
        for (int i = 0; i < 4; ++i)
            #pragma unroll
            for (int j = 0; j < 4; ++j)
                acc[i][j] = __builtin_amdgcn_mfma_f32_16x16x32_bf16(af[i], bfr[j], acc[i][j], 0, 0, 0);
        __syncthreads();
    }

    int crow0 = (lane >> 4) * 4;
    int ccol = lane & 15;

    if (Cb && !Cf) {
        // LDS-bounce coalesced epilogue, two 64-row halves
        #pragma unroll
        for (int hh = 0; hh < 2; ++hh) {
            if (hh) __syncthreads();               // protect previous half's reads
            if (wr == hh) {
                #pragma unroll
                for (int i = 0; i < 4; ++i) {
                    #pragma unroll
                    for (int r = 0; r < 4; ++r) {
                        int lrow = i * 16 + crow0 + r;          // 0..63
                        #pragma unroll
                        for (int j = 0; j < 4; ++j) {
                            int lcol = wc * 64 + j * 16 + ccol; // 0..127
                            float v = acc[i][j][r];
                            if (bias) v += bias[bcol + lcol];
                            if (act) v = gelu_f(v);
                            lds[lrow * BP + lcol] = f2b(v);
                        }
                    }
                }
            }
            __syncthreads();
            int lrow = tid >> 2;                    // 0..63
            int off8 = (tid & 3) * 32;              // ushort offset 0/32/64/96
            int grow = brow + hh * 64 + lrow;
            if (grow < n) {
                uint4* dp = (uint4*)&Cb[(long)grow * ldc + bcol + off8];
                const uint4* sp = (const uint4*)&lds[lrow * BP + off8];
                dp[0] = sp[0]; dp[1] = sp[1]; dp[2] = sp[2]; dp[3] = sp[3];
            }
        }
        return;
    }

    #pragma unroll
    for (int i = 0; i < 4; ++i) {
        #pragma unroll
        for (int r = 0; r < 4; ++r) {
            int grow = brow + wr * 64 + i * 16 + crow0 + r;
            if (grow >= n) continue;
            #pragma unroll
            for (int j = 0; j < 4; ++j) {
                int gcol = bcol + wc * 64 + j * 16 + ccol;
                float v = acc[i][j][r];
                if (bias) v += bias[gcol];
                if (act) v = gelu_f(v);
                if (res) v += res[(long)grow * ldr + gcol];
                if (Cf) Cf[(long)grow * ldc + gcol] = v;
                if (Cb) Cb[(long)grow * ldc + gcol] = f2b(v);
            }
        }
    }
}

// ---------------- LayerNorm rows of 256; input fp32 (af) or bf16 (ab) ----------------
__global__ __launch_bounds__(256) void ln256_kernel(
    const float* __restrict__ af, const ushort* __restrict__ ab,
    const float* __restrict__ res,
    const float* __restrict__ g, const float* __restrict__ bta,
    float* __restrict__ outf, ushort* __restrict__ outb, int n, int post_gelu)
{
    int row = blockIdx.x * 4 + (threadIdx.x >> 6);
    if (row >= n) return;
    int lane = threadIdx.x & 63;
    float4 v;
    if (af) {
        v = *(const float4*)(af + (long)row * H + lane * 4);
    } else {
        ushort4 vb = *(const ushort4*)(ab + (long)row * H + lane * 4);
        v.x = b2f(vb.x); v.y = b2f(vb.y); v.z = b2f(vb.z); v.w = b2f(vb.w);
    }
    if (res) {
        float4 r = *(const float4*)(res + (long)row * H + lane * 4);
        v.x += r.x; v.y += r.y; v.z += r.z; v.w += r.w;
    }
    float s = v.x + v.y + v.z + v.w;
    #pragma unroll
    for (int off = 1; off < 64; off <<= 1) s += __shfl_xor(s, off);
    float mean = s * (1.0f / H);
    float dx = v.x - mean, dy = v.y - mean, dz = v.z - mean, dw = v.w - mean;
    float qs = dx * dx + dy * dy + dz * dz + dw * dw;
    #pragma unroll
    for (int off = 1; off < 64; off <<= 1) qs += __shfl_xor(qs, off);
    float rstd = rsqrtf(qs * (1.0f / H) + 1e-5f);
    float4 gg = *(const float4*)(g + lane * 4);
    float4 bb = *(const float4*)(bta + lane * 4);
    float4 o;
    o.x = dx * rstd * gg.x + bb.x;
    o.y = dy * rstd * gg.y + bb.y;
    o.z = dz * rstd * gg.z + bb.z;
    o.w = dw * rstd * gg.w + bb.w;
    if (post_gelu) { o.x = gelu_f(o.x); o.y = gelu_f(o.y); o.z = gelu_f(o.z); o.w = gelu_f(o.w); }
    if (outf) *(float4*)(outf + (long)row * H + lane * 4) = o;
    if (outb) {
        ushort4 ob = { f2b(o.x), f2b(o.y), f2b(o.z), f2b(o.w) };
        *(ushort4*)(outb + (long)row * H + lane * 4) = ob;
    }
}

// ---------------- conversions ----------------
__global__ __launch_bounds__(256) void xcast_kernel(const float* __restrict__ x,
                                                    ushort* __restrict__ xb)
{
    long i = (long)blockIdx.x * 256 + threadIdx.x;
    if (i >= (long)NN * KIN) return;
    int n = (int)(i / KIN), c = (int)(i % KIN);
    xb[i] = (c < FIN) ? f2b(x[(long)n * FIN + c]) : (ushort)0;
}

__global__ __launch_bounds__(256) void wtin_kernel(const float* __restrict__ W,
                                                   ushort* __restrict__ Wt)
{
    int i = blockIdx.x * 256 + threadIdx.x;
    if (i >= 256 * KIN) return;
    int m = i / KIN, k = i % KIN;
    Wt[i] = (k < FIN) ? f2b(W[(long)k * H + m]) : (ushort)0;
}

__global__ __launch_bounds__(256) void wtqkv_kernel(
    const float* __restrict__ Wq, const float* __restrict__ Wk,
    const float* __restrict__ Wv, ushort* __restrict__ out)
{
    long i = (long)blockIdx.x * 256 + threadIdx.x;
    if (i >= (long)LAYERS * 768 * 256) return;
    int l = (int)(i / (768 * 256));
    int r = (int)(i % (768 * 256));
    int m = r >> 8, k = r & 255;
    const float* W = (m < 256) ? Wq : ((m < 512) ? Wk : Wv);
    out[i] = f2b(W[(long)l * 65536 + (long)k * 256 + (m & 255)]);
}

__global__ __launch_bounds__(256) void wtgen_kernel(
    const float* __restrict__ W, ushort* __restrict__ out, int L, int K, int M)
{
    long i = (long)blockIdx.x * 256 + threadIdx.x;
    if (i >= (long)L * K * M) return;
    int l = (int)(i / ((long)K * M));
    int r = (int)(i % ((long)K * M));
    int m = r / K, k = r % K;
    out[i] = f2b(W[(long)l * K * M + (long)k * M + m]);
}

// ---------------- CSR build ----------------
__global__ __launch_bounds__(256) void deg_kernel(const int* __restrict__ dst,
                                                   int* __restrict__ deg)
{
    int e = blockIdx.x * 256 + threadIdx.x;
    if (e >= NE) return;
    atomicAdd(&deg[dst[e]], 1);
}

__global__ __launch_bounds__(256) void scan1_kernel(const int* __restrict__ deg,
                                                     int* __restrict__ rowptr,
                                                     int* __restrict__ bsum)
{
    __shared__ int buf[256];
    int tid = threadIdx.x;
    int i = blockIdx.x * 256 + tid;
    int v = (i < NN) ? deg[i] : 0;
    buf[tid] = v;
    __syncthreads();
    #pragma unroll
    for (int off = 1; off < 256; off <<= 1) {
        int t = (tid >= off) ? buf[tid - off] : 0;
        __syncthreads();
        buf[tid] += t;
        __syncthreads();
    }
    if (i < NN) rowptr[i] = buf[tid] - v;
    if (tid == 255) bsum[blockIdx.x] = buf[255];
}

__global__ __launch_bounds__(256) void scan2_kernel(int* __restrict__ bsum, int nb)
{
    __shared__ int buf[256];
    int tid = threadIdx.x;
    int v = (tid < nb) ? bsum[tid] : 0;
    buf[tid] = v;
    __syncthreads();
    #pragma unroll
    for (int off = 1; off < 256; off <<= 1) {
        int t = (tid >= off) ? buf[tid - off] : 0;
        __syncthreads();
        buf[tid] += t;
        __syncthreads();
    }
    if (tid < nb) bsum[tid] = buf[tid] - v;
}

__global__ __launch_bounds__(256) void scan3_kernel(int* __restrict__ rowptr,
                                                     const int* __restrict__ bsum)
{
    int i = blockIdx.x * 256 + threadIdx.x;
    if (i < NN) rowptr[i] += bsum[blockIdx.x];
    if (i == 0) rowptr[NN] = NE;
}

__global__ __launch_bounds__(256) void fill_kernel(
    const int* __restrict__ src, const int* __restrict__ dst,
    const float* __restrict__ ea, const int* __restrict__ rowptr,
    int* __restrict__ cursor, int* __restrict__ csr_src,
    float2* __restrict__ csr_ea)
{
    int e = blockIdx.x * 256 + threadIdx.x;
    if (e >= NE) return;
    int d = dst[e];
    int pos = atomicAdd(&cursor[d], 1);
    int j = rowptr[d] + pos;
    csr_src[j] = src[e];
    csr_ea[j] = *(const float2*)(ea + 2 * e);
}

// ---------------- fused gather attention (one wave per node, all 8 heads) ----------------
__global__ __launch_bounds__(256) void attn_kernel(
    const ushort* __restrict__ qkv,
    const int* __restrict__ rowptr, const int* __restrict__ csr_src,
    const float2* __restrict__ csr_ea,
    const float* __restrict__ We, const float* __restrict__ be,
    ushort* __restrict__ aggb)
{
    int node = blockIdx.x * 4 + (threadIdx.x >> 6);
    if (node >= NN) return;
    int lane = threadIdx.x & 63;
    int h = lane >> 3;                 // global head 0..7
    float w0 = We[h], w1 = We[8 + h], bb = be[h];

    uint2 q2 = *(const uint2*)(qkv + (long)node * 768 + lane * 4);
    int jbeg = rowptr[node], jend = rowptr[node + 1];

    float m = -1e30f, l = 0.f;
    float a0 = 0.f, a1 = 0.f, a2 = 0.f, a3 = 0.f;

    uint2 kN, vN; float2 eaN;
    if (jbeg < jend) {
        int s0 = csr_src[jbeg];
        eaN = csr_ea[jbeg];
        const ushort* kr = qkv + (long)s0 * 768 + 256;
        kN = *(const uint2*)(kr + lane * 4);
        vN = *(const uint2*)(kr + 256 + lane * 4);
    }
    for (int j = jbeg; j < jend; ++j) {
        uint2 k2 = kN, v2 = vN; float2 eab = eaN;
        if (j + 1 < jend) {
            int s1 = csr_src[j + 1];
            eaN = csr_ea[j + 1];
            const ushort* kr = qkv + (long)s1 * 768 + 256;
            kN = *(const uint2*)(kr + lane * 4);
            vN = *(const uint2*)(kr + 256 + lane * 4);
        }
        float p = dot2b(q2.x, k2.x) + dot2b(q2.y, k2.y);
        p += __shfl_xor(p, 1);
        p += __shfl_xor(p, 2);
        p += __shfl_xor(p, 4);         // sum over 8 lanes = 32 channels
        float sc = p * INV_SCALE + eab.x * w0 + eab.y * w1 + bb;
        float vx = __uint_as_float(v2.x << 16);
        float vy = __uint_as_float(v2.x & 0xffff0000u);
        float vz = __uint_as_float(v2.y << 16);
        float vw = __uint_as_float(v2.y & 0xffff0000u);
        float mn = fmaxf(m, sc);
        float scale = __expf(m - mn);
        float e = __expf(sc - mn);
        l = l * scale + e;
        a0 = a0 * scale + e * vx;
        a1 = a1 * scale + e * vy;
        a2 = a2 * scale + e * vz;
        a3 = a3 * scale + e * vw;
        m = mn;
    }
    float inv = 1.0f / (l + 1e-16f);
    ushort4 o = { f2b(a0 * inv), f2b(a1 * inv), f2b(a2 * inv), f2b(a3 * inv) };
    *(ushort4*)(aggb + (long)node * 256 + lane * 4) = o;
}

// ---------------- classifier tail ----------------
__global__ __launch_bounds__(256) void cls_kernel(
    const float* __restrict__ t1, const float* __restrict__ W,
    const float* __restrict__ b, float* __restrict__ out)
{
    int i = blockIdx.x * 256 + threadIdx.x;
    if (i >= NN) return;
    const float* tp = t1 + (long)i * 128;
    float a0 = 0.f, a1 = 0.f;
    #pragma unroll
    for (int j = 0; j < 128; j += 4) {
        float4 t = *(const float4*)(tp + j);
        a0 += t.x * W[(j + 0) * 2] + t.y * W[(j + 1) * 2] + t.z * W[(j + 2) * 2] + t.w * W[(j + 3) * 2];
        a1 += t.x * W[(j + 0) * 2 + 1] + t.y * W[(j + 1) * 2 + 1] + t.z * W[(j + 2) * 2 + 1] + t.w * W[(j + 3) * 2 + 1];
    }
    float l0 = a0 + b[0], l1 = a1 + b[1];
    out[(long)i * 2 + 0] = l0;
    out[(long)i * 2 + 1] = l1;
    float mx = fmaxf(l0, l1);
    float p0 = expf(l0 - mx), p1 = expf(l1 - mx);
    float sden = p0 + p1;
    out[2L * NN + (long)i * 2 + 0] = p0 / sden;
    out[2L * NN + (long)i * 2 + 1] = p1 / sden;
}

extern "C" void kernel_launch(void* const* d_in, const int* in_sizes, int n_in,
                              void* d_out, int out_size, void* d_ws, size_t ws_size,
                              hipStream_t stream) {
    const float* x      = (const float*)d_in[0];
    const int*   ei     = (const int*)d_in[1];
    const float* ea     = (const float*)d_in[2];
    const float* in_W   = (const float*)d_in[3];
    const float* in_b   = (const float*)d_in[4];
    const float* in_g   = (const float*)d_in[5];
    const float* in_bb  = (const float*)d_in[6];
    const float* Wq     = (const float*)d_in[7];
    const float* Wk     = (const float*)d_in[8];
    const float* Wv     = (const float*)d_in[9];
    const float* We     = (const float*)d_in[10];
    const float* be     = (const float*)d_in[11];
    const float* Wo     = (const float*)d_in[12];
    const float* bo     = (const float*)d_in[13];
    const float* ln1_g  = (const float*)d_in[14];
    const float* ln1_b  = (const float*)d_in[15];
    const float* ln2_g  = (const float*)d_in[16];
    const float* ln2_b  = (const float*)d_in[17];
    const float* f1_W   = (const float*)d_in[18];
    const float* f1_b   = (const float*)d_in[19];
    const float* f2_W   = (const float*)d_in[20];
    const float* f2_b   = (const float*)d_in[21];
    const float* cls1_W = (const float*)d_in[22];
    const float* cls1_b = (const float*)d_in[23];
    const float* cls2_W = (const float*)d_in[24];
    const float* cls2_b = (const float*)d_in[25];
    float* out = (float*)d_out;

    const int* src = ei;
    const int* dst = ei + NE;

    // ---- workspace layout (~197 MB) ----
    char* w = (char*)d_ws;
    float* B0 = (float*)w;            w += (size_t)NN * H * 4;       // h / out (fp32)
    ushort* hb = (ushort*)w;          w += (size_t)NN * H * 2;       // bf16 activations
    char* pool = w;                   w += (size_t)NN * 1024 * 2;    // 102.4 MB union
    ushort* qkv  = (ushort*)pool;                                    // N x 768 bf16
    ushort* aggb = (ushort*)(pool + (size_t)NN * 768 * 2);           // N x 256 bf16
    float*  tproj = (float*)pool;                                    // input-proj t
    ushort* xb   = (ushort*)(pool + (size_t)NN * H * 4);             // N x 224 bf16
    ushort* tb   = (ushort*)pool;                                    // FFN N x 1024 bf16
    float*  t1   = (float*)pool;                                     // cls hidden fp32
    int* deg    = (int*)w;            w += (size_t)NN * 4;
    int* cursor = (int*)w;            w += (size_t)NN * 4;
    int* rowptr = (int*)w;            w += (size_t)(NN + 2) * 4;
    int* bsum   = (int*)w;            w += 1024;
    int* csr_src = (int*)w;           w += (size_t)NE * 4;
    float2* csr_ea = (float2*)w;      w += (size_t)NE * 8;
    ushort* wqkv_t = (ushort*)w;      w += (size_t)LAYERS * 768 * 256 * 2;
    ushort* wo_t  = (ushort*)w;       w += (size_t)LAYERS * 65536 * 2;
    ushort* f1_t  = (ushort*)w;       w += (size_t)LAYERS * 262144 * 2;
    ushort* f2_t  = (ushort*)w;       w += (size_t)LAYERS * 262144 * 2;
    ushort* c1_t  = (ushort*)w;       w += (size_t)32768 * 2;
    ushort* inw_t = (ushort*)w;       w += (size_t)256 * KIN * 2;

    dim3 blk(256);
    const int ln_grid = (NN + 3) / 4;
    const int e_grid = (NE + 255) / 256;
    const int n_grid = (NN + 255) / 256;
    const int ty = (NN + 127) / 128;

    // ---- CSR build ----
    hipMemsetAsync(deg, 0, (size_t)NN * 4, stream);
    hipMemsetAsync(cursor, 0, (size_t)NN * 4, stream);
    deg_kernel<<<e_grid, blk, 0, stream>>>(dst, deg);
    scan1_kernel<<<n_grid, blk, 0, stream>>>(deg, rowptr, bsum);
    scan2_kernel<<<1, blk, 0, stream>>>(bsum, n_grid);
    scan3_kernel<<<n_grid, blk, 0, stream>>>(rowptr, bsum);
    fill_kernel<<<e_grid, blk, 0, stream>>>(src, dst, ea, rowptr, cursor, csr_src, csr_ea);

    // ---- weight convert/transpose ----
    wtqkv_kernel<<<(int)(((long)LAYERS * 768 * 256 + 255) / 256), blk, 0, stream>>>(Wq, Wk, Wv, wqkv_t);
    wtgen_kernel<<<(int)(((long)LAYERS * 65536 + 255) / 256), blk, 0, stream>>>(Wo, wo_t, LAYERS, 256, 256);
    wtgen_kernel<<<(int)(((long)LAYERS * 262144 + 255) / 256), blk, 0, stream>>>(f1_W, f1_t, LAYERS, 256, 1024);
    wtgen_kernel<<<(int)(((long)LAYERS * 262144 + 255) / 256), blk, 0, stream>>>(f2_W, f2_t, LAYERS, 1024, 256);
    wtgen_kernel<<<(32768 + 255) / 256, blk, 0, stream>>>(cls1_W, c1_t, 1, 256, 128);
    wtin_kernel<<<(256 * KIN + 255) / 256, blk, 0, stream>>>(in_W, inw_t);

    // ---- input projection (MFMA) ----
    xcast_kernel<<<(int)(((long)NN * KIN + 255) / 256), blk, 0, stream>>>(x, xb);
    {
        dim3 g(2, ty);
        gemm_bf16_kernel<<<g, blk, 0, stream>>>(xb, KIN, inw_t, in_b, nullptr, 0,
                                                tproj, nullptr, H, NN, KIN, 0);
        ln256_kernel<<<ln_grid, blk, 0, stream>>>(tproj, nullptr, nullptr, in_g, in_bb, B0, nullptr, NN, 1);
    }

    for (int l = 0; l < LAYERS; ++l) {
        const float* we  = We + (long)l * 16;
        const float* bel = be + (long)l * 8;
        const float* bol = bo + (long)l * H;
        const float* g1 = ln1_g + (long)l * H;
        const float* b1 = ln1_b + (long)l * H;
        const float* g2 = ln2_g + (long)l * H;
        const float* b2 = ln2_b + (long)l * H;
        const float* bf1 = f1_b + (long)l * FF;
        const float* bf2 = f2_b + (long)l * H;

        // hb = bf16(LN1(h))
        ln256_kernel<<<ln_grid, blk, 0, stream>>>(B0, nullptr, nullptr, g1, b1, nullptr, hb, NN, 0);

        // fused QKV (M=768) + 8-head gather attention
        dim3 gq(6, ty);
        gemm_bf16_kernel<<<gq, blk, 0, stream>>>(hb, H, wqkv_t + (long)l * 768 * 256,
            nullptr, nullptr, 0, nullptr, qkv, 768, NN, H, 0);
        attn_kernel<<<(NN + 3) / 4, blk, 0, stream>>>(qkv, rowptr, csr_src, csr_ea, we, bel, aggb);

        // B0 = LN(aggb@Wo^T + bo + h); hb = bf16(out)
        dim3 gh(2, ty);
        gemm_bf16_kernel<<<gh, blk, 0, stream>>>(aggb, H, wo_t + (long)l * 65536,
            bol, nullptr, 0, nullptr, qkv, H, NN, H, 0);   // reuse qkv head as woo
        ln256_kernel<<<ln_grid, blk, 0, stream>>>(nullptr, qkv, B0, g2, b2, B0, hb, NN, 0);

        // FFN one-shot: tb = gelu(hb@f1^T+b) bf16 ; B0 = tb@f2^T + b + B0
        dim3 gf(8, ty);
        gemm_bf16_kernel<<<gf, blk, 0, stream>>>(hb, H, f1_t + (long)l * 262144,
            bf1, nullptr, 0, nullptr, tb, FF, NN, H, 1);
        dim3 gb(2, ty);
        gemm_bf16_kernel<<<gb, blk, 0, stream>>>(tb, FF, f2_t + (long)l * 262144,
            bf2, B0, H, B0, (l == LAYERS - 1) ? hb : nullptr, H, NN, FF, 0);
    }

    // ---- classifier ----
    {
        dim3 g(1, ty);
        gemm_bf16_kernel<<<g, blk, 0, stream>>>(hb, H, c1_t, cls1_b, nullptr, 0, t1, nullptr, 128, NN, H, 1);
        cls_kernel<<<n_grid, blk, 0, stream>>>(t1, cls2_W, cls2_b, out);
    }
}

// Round 11
// 2939.794 us; speedup vs baseline: 1.0638x; 1.0638x over previous
//
#include <hip/hip_runtime.h>
#include <math.h>

#define NN 50000
#define NE 800000
#define FIN 197
#define KIN 224          // FIN zero-padded to multiple of 32
#define H 256
#define HEADS 8
#define HD 32
#define LAYERS 5
#define FF 1024
#define INV_SCALE 0.17677669529663687f   // 1/sqrt(32)

typedef __attribute__((ext_vector_type(8))) short short8;
typedef __attribute__((ext_vector_type(4))) float f32x4;
typedef unsigned short ushort;

// fast GELU via exp2/rcp (max abs err ~3e-4 vs exact erf form)
__device__ __forceinline__ float gelu_f(float x) {
    float x2 = x * x;
    float u = __builtin_fmaf(0.044715f * x2, x, x);
    float e = __builtin_amdgcn_exp2f(-2.3022075f * u);
    return x * __builtin_amdgcn_rcpf(1.0f + e);
}
__device__ __forceinline__ ushort f2b(float f) {        // fp32 -> bf16 RNE
    unsigned u = __float_as_uint(f);
    u += 0x7fffu + ((u >> 16) & 1u);
    return (ushort)(u >> 16);
}
__device__ __forceinline__ float b2f(ushort b) {
    return __uint_as_float(((unsigned)b) << 16);
}
__device__ __forceinline__ float dot2b(unsigned a, unsigned b) {  // 2 packed bf16 pairs
    float a0 = __uint_as_float(a << 16), a1 = __uint_as_float(a & 0xffff0000u);
    float b0 = __uint_as_float(b << 16), b1 = __uint_as_float(b & 0xffff0000u);
    return a0 * b0 + a1 * b1;
}

// ---------------- MFMA bf16 GEMM: C = act(A @ Bt^T + bias) + res ----------------
// 1-D grid of gx*gy blocks with XCD-aware swizzle: the gx column-blocks that
// share one A row-tile get linear ids == same value mod 8 -> same XCD -> the
// A-tile is fetched into that XCD's L2 once (round-9 counters: f1 FETCH=100MB
// for 25.6MB A, QKV 127MB -- redundant cross-XCD A re-fetch was ~50% of the
// GEMM dispatch traffic).
#define LDSP 40
__global__ __launch_bounds__(256) void gemm_bf16_kernel(
    const ushort* __restrict__ A, int lda,
    const ushort* __restrict__ Bt,
    const float* __restrict__ bias,
    const float* __restrict__ res, int ldr,
    float* __restrict__ Cf, ushort* __restrict__ Cb, int ldc,
    int n, int K, int act, int gx)
{
    __shared__ ushort As[128 * LDSP];
    __shared__ ushort Bs[128 * LDSP];
    int tid = threadIdx.x;
    int lane = tid & 63;
    int wave = tid >> 6;
    int wr = wave >> 1, wc = wave & 1;

    // swizzled block mapping: groups of (8 row-tiles x gx col-tiles)
    int tiles_y = (n + 127) >> 7;
    int lin = blockIdx.x;
    int gsz = gx * 8;
    int group = lin / gsz;
    int rem = lin - group * gsz;
    int rows_left = tiles_y - group * 8;
    int rg = rows_left < 8 ? rows_left : 8;
    int r = rem % rg;
    int c = rem / rg;
    int brow = (group * 8 + r) * 128;
    int bcol = c * 128;

    f32x4 acc[4][4] = {};
    int m0 = lane & 15;
    int koff = (lane >> 4) * 8;

    for (int k0 = 0; k0 < K; k0 += 32) {
        #pragma unroll
        for (int p = 0; p < 2; ++p) {
            int chunk = tid + p * 256;
            int row = chunk >> 2;
            int col8 = (chunk & 3) * 8;
            int gr = brow + row; if (gr >= n) gr = n - 1;
            *(uint4*)&As[row * LDSP + col8] = *(const uint4*)&A[(long)gr * lda + k0 + col8];
            *(uint4*)&Bs[row * LDSP + col8] = *(const uint4*)&Bt[(long)(bcol + row) * K + k0 + col8];
        }
        __syncthreads();
        short8 af[4], bfr[4];
        #pragma unroll
        for (int i = 0; i < 4; ++i)
            af[i] = *(const short8*)&As[(wr * 64 + i * 16 + m0) * LDSP + koff];
        #pragma unroll
        for (int j = 0; j < 4; ++j)
            bfr[j] = *(const short8*)&Bs[(wc * 64 + j * 16 + m0) * LDSP + koff];
        #pragma unroll
        for (int i = 0; i < 4; ++i)
            #pragma unroll
            for (int j = 0; j < 4; ++j)
                acc[i][j] = __builtin_amdgcn_mfma_f32_16x16x32_bf16(af[i], bfr[j], acc[i][j], 0, 0, 0);
        __syncthreads();
    }

    int crow0 = (lane >> 4) * 4;
    int ccol = lane & 15;
    #pragma unroll
    for (int i = 0; i < 4; ++i) {
        #pragma unroll
        for (int rr = 0; rr < 4; ++rr) {
            int grow = brow + wr * 64 + i * 16 + crow0 + rr;
            if (grow >= n) continue;
            #pragma unroll
            for (int j = 0; j < 4; ++j) {
                int gcol = bcol + wc * 64 + j * 16 + ccol;
                float v = acc[i][j][rr];
                if (bias) v += bias[gcol];
                if (act) v = gelu_f(v);
                if (res) v += res[(long)grow * ldr + gcol];
                if (Cf) Cf[(long)grow * ldc + gcol] = v;
                if (Cb) Cb[(long)grow * ldc + gcol] = f2b(v);
            }
        }
    }
}

// ---------------- LayerNorm rows of 256; input fp32 (af) or bf16 (ab) ----------------
__global__ __launch_bounds__(256) void ln256_kernel(
    const float* __restrict__ af, const ushort* __restrict__ ab,
    const float* __restrict__ res,
    const float* __restrict__ g, const float* __restrict__ bta,
    float* __restrict__ outf, ushort* __restrict__ outb, int n, int post_gelu)
{
    int row = blockIdx.x * 4 + (threadIdx.x >> 6);
    if (row >= n) return;
    int lane = threadIdx.x & 63;
    float4 v;
    if (af) {
        v = *(const float4*)(af + (long)row * H + lane * 4);
    } else {
        ushort4 vb = *(const ushort4*)(ab + (long)row * H + lane * 4);
        v.x = b2f(vb.x); v.y = b2f(vb.y); v.z = b2f(vb.z); v.w = b2f(vb.w);
    }
    if (res) {
        float4 r = *(const float4*)(res + (long)row * H + lane * 4);
        v.x += r.x; v.y += r.y; v.z += r.z; v.w += r.w;
    }
    float s = v.x + v.y + v.z + v.w;
    #pragma unroll
    for (int off = 1; off < 64; off <<= 1) s += __shfl_xor(s, off);
    float mean = s * (1.0f / H);
    float dx = v.x - mean, dy = v.y - mean, dz = v.z - mean, dw = v.w - mean;
    float qs = dx * dx + dy * dy + dz * dz + dw * dw;
    #pragma unroll
    for (int off = 1; off < 64; off <<= 1) qs += __shfl_xor(qs, off);
    float rstd = rsqrtf(qs * (1.0f / H) + 1e-5f);
    float4 gg = *(const float4*)(g + lane * 4);
    float4 bb = *(const float4*)(bta + lane * 4);
    float4 o;
    o.x = dx * rstd * gg.x + bb.x;
    o.y = dy * rstd * gg.y + bb.y;
    o.z = dz * rstd * gg.z + bb.z;
    o.w = dw * rstd * gg.w + bb.w;
    if (post_gelu) { o.x = gelu_f(o.x); o.y = gelu_f(o.y); o.z = gelu_f(o.z); o.w = gelu_f(o.w); }
    if (outf) *(float4*)(outf + (long)row * H + lane * 4) = o;
    if (outb) {
        ushort4 ob = { f2b(o.x), f2b(o.y), f2b(o.z), f2b(o.w) };
        *(ushort4*)(outb + (long)row * H + lane * 4) = ob;
    }
}

// ---------------- conversions ----------------
__global__ __launch_bounds__(256) void xcast_kernel(const float* __restrict__ x,
                                                    ushort* __restrict__ xb)
{
    long i = (long)blockIdx.x * 256 + threadIdx.x;
    if (i >= (long)NN * KIN) return;
    int n = (int)(i / KIN), c = (int)(i % KIN);
    xb[i] = (c < FIN) ? f2b(x[(long)n * FIN + c]) : (ushort)0;
}

__global__ __launch_bounds__(256) void wtin_kernel(const float* __restrict__ W,
                                                   ushort* __restrict__ Wt)
{
    int i = blockIdx.x * 256 + threadIdx.x;
    if (i >= 256 * KIN) return;
    int m = i / KIN, k = i % KIN;
    Wt[i] = (k < FIN) ? f2b(W[(long)k * H + m]) : (ushort)0;
}

__global__ __launch_bounds__(256) void wtqkv_kernel(
    const float* __restrict__ Wq, const float* __restrict__ Wk,
    const float* __restrict__ Wv, ushort* __restrict__ out)
{
    long i = (long)blockIdx.x * 256 + threadIdx.x;
    if (i >= (long)LAYERS * 768 * 256) return;
    int l = (int)(i / (768 * 256));
    int r = (int)(i % (768 * 256));
    int m = r >> 8, k = r & 255;
    const float* W = (m < 256) ? Wq : ((m < 512) ? Wk : Wv);
    out[i] = f2b(W[(long)l * 65536 + (long)k * 256 + (m & 255)]);
}

__global__ __launch_bounds__(256) void wtgen_kernel(
    const float* __restrict__ W, ushort* __restrict__ out, int L, int K, int M)
{
    long i = (long)blockIdx.x * 256 + threadIdx.x;
    if (i >= (long)L * K * M) return;
    int l = (int)(i / ((long)K * M));
    int r = (int)(i % ((long)K * M));
    int m = r / K, k = r % K;
    out[i] = f2b(W[(long)l * K * M + (long)k * M + m]);
}

// ---------------- CSR build ----------------
__global__ __launch_bounds__(256) void deg_kernel(const int* __restrict__ dst,
                                                   int* __restrict__ deg)
{
    int e = blockIdx.x * 256 + threadIdx.x;
    if (e >= NE) return;
    atomicAdd(&deg[dst[e]], 1);
}

__global__ __launch_bounds__(256) void scan1_kernel(const int* __restrict__ deg,
                                                     int* __restrict__ rowptr,
                                                     int* __restrict__ bsum)
{
    __shared__ int buf[256];
    int tid = threadIdx.x;
    int i = blockIdx.x * 256 + tid;
    int v = (i < NN) ? deg[i] : 0;
    buf[tid] = v;
    __syncthreads();
    #pragma unroll
    for (int off = 1; off < 256; off <<= 1) {
        int t = (tid >= off) ? buf[tid - off] : 0;
        __syncthreads();
        buf[tid] += t;
        __syncthreads();
    }
    if (i < NN) rowptr[i] = buf[tid] - v;
    if (tid == 255) bsum[blockIdx.x] = buf[255];
}

__global__ __launch_bounds__(256) void scan2_kernel(int* __restrict__ bsum, int nb)
{
    __shared__ int buf[256];
    int tid = threadIdx.x;
    int v = (tid < nb) ? bsum[tid] : 0;
    buf[tid] = v;
    __syncthreads();
    #pragma unroll
    for (int off = 1; off < 256; off <<= 1) {
        int t = (tid >= off) ? buf[tid - off] : 0;
        __syncthreads();
        buf[tid] += t;
        __syncthreads();
    }
    if (tid < nb) bsum[tid] = buf[tid] - v;
}

__global__ __launch_bounds__(256) void scan3_kernel(int* __restrict__ rowptr,
                                                     const int* __restrict__ bsum)
{
    int i = blockIdx.x * 256 + threadIdx.x;
    if (i < NN) rowptr[i] += bsum[blockIdx.x];
    if (i == 0) rowptr[NN] = NE;
}

__global__ __launch_bounds__(256) void fill_kernel(
    const int* __restrict__ src, const int* __restrict__ dst,
    const float* __restrict__ ea, const int* __restrict__ rowptr,
    int* __restrict__ cursor, int* __restrict__ csr_src,
    float2* __restrict__ csr_ea)
{
    int e = blockIdx.x * 256 + threadIdx.x;
    if (e >= NE) return;
    int d = dst[e];
    int pos = atomicAdd(&cursor[d], 1);
    int j = rowptr[d] + pos;
    csr_src[j] = src[e];
    csr_ea[j] = *(const float2*)(ea + 2 * e);
}

// ---------------- fused gather attention (one wave per node, all 8 heads) ----------------
__global__ __launch_bounds__(256) void attn_kernel(
    const ushort* __restrict__ qkv,
    const int* __restrict__ rowptr, const int* __restrict__ csr_src,
    const float2* __restrict__ csr_ea,
    const float* __restrict__ We, const float* __restrict__ be,
    ushort* __restrict__ aggb)
{
    int node = blockIdx.x * 4 + (threadIdx.x >> 6);
    if (node >= NN) return;
    int lane = threadIdx.x & 63;
    int h = lane >> 3;                 // global head 0..7
    float w0 = We[h], w1 = We[8 + h], bb = be[h];

    uint2 q2 = *(const uint2*)(qkv + (long)node * 768 + lane * 4);
    int jbeg = rowptr[node], jend = rowptr[node + 1];

    float m = -1e30f, l = 0.f;
    float a0 = 0.f, a1 = 0.f, a2 = 0.f, a3 = 0.f;

    uint2 kN, vN; float2 eaN;
    if (jbeg < jend) {
        int s0 = csr_src[jbeg];
        eaN = csr_ea[jbeg];
        const ushort* kr = qkv + (long)s0 * 768 + 256;
        kN = *(const uint2*)(kr + lane * 4);
        vN = *(const uint2*)(kr + 256 + lane * 4);
    }
    for (int j = jbeg; j < jend; ++j) {
        uint2 k2 = kN, v2 = vN; float2 eab = eaN;
        if (j + 1 < jend) {
            int s1 = csr_src[j + 1];
            eaN = csr_ea[j + 1];
            const ushort* kr = qkv + (long)s1 * 768 + 256;
            kN = *(const uint2*)(kr + lane * 4);
            vN = *(const uint2*)(kr + 256 + lane * 4);
        }
        float p = dot2b(q2.x, k2.x) + dot2b(q2.y, k2.y);
        p += __shfl_xor(p, 1);
        p += __shfl_xor(p, 2);
        p += __shfl_xor(p, 4);         // sum over 8 lanes = 32 channels
        float sc = p * INV_SCALE + eab.x * w0 + eab.y * w1 + bb;
        float vx = __uint_as_float(v2.x << 16);
        float vy = __uint_as_float(v2.x & 0xffff0000u);
        float vz = __uint_as_float(v2.y << 16);
        float vw = __uint_as_float(v2.y & 0xffff0000u);
        float mn = fmaxf(m, sc);
        float scale = __expf(m - mn);
        float e = __expf(sc - mn);
        l = l * scale + e;
        a0 = a0 * scale + e * vx;
        a1 = a1 * scale + e * vy;
        a2 = a2 * scale + e * vz;
        a3 = a3 * scale + e * vw;
        m = mn;
    }
    float inv = 1.0f / (l + 1e-16f);
    ushort4 o = { f2b(a0 * inv), f2b(a1 * inv), f2b(a2 * inv), f2b(a3 * inv) };
    *(ushort4*)(aggb + (long)node * 256 + lane * 4) = o;
}

// ---------------- classifier tail ----------------
__global__ __launch_bounds__(256) void cls_kernel(
    const float* __restrict__ t1, const float* __restrict__ W,
    const float* __restrict__ b, float* __restrict__ out)
{
    int i = blockIdx.x * 256 + threadIdx.x;
    if (i >= NN) return;
    const float* tp = t1 + (long)i * 128;
    float a0 = 0.f, a1 = 0.f;
    #pragma unroll
    for (int j = 0; j < 128; j += 4) {
        float4 t = *(const float4*)(tp + j);
        a0 += t.x * W[(j + 0) * 2] + t.y * W[(j + 1) * 2] + t.z * W[(j + 2) * 2] + t.w * W[(j + 3) * 2];
        a1 += t.x * W[(j + 0) * 2 + 1] + t.y * W[(j + 1) * 2 + 1] + t.z * W[(j + 2) * 2 + 1] + t.w * W[(j + 3) * 2 + 1];
    }
    float l0 = a0 + b[0], l1 = a1 + b[1];
    out[(long)i * 2 + 0] = l0;
    out[(long)i * 2 + 1] = l1;
    float mx = fmaxf(l0, l1);
    float p0 = expf(l0 - mx), p1 = expf(l1 - mx);
    float sden = p0 + p1;
    out[2L * NN + (long)i * 2 + 0] = p0 / sden;
    out[2L * NN + (long)i * 2 + 1] = p1 / sden;
}

extern "C" void kernel_launch(void* const* d_in, const int* in_sizes, int n_in,
                              void* d_out, int out_size, void* d_ws, size_t ws_size,
                              hipStream_t stream) {
    const float* x      = (const float*)d_in[0];
    const int*   ei     = (const int*)d_in[1];
    const float* ea     = (const float*)d_in[2];
    const float* in_W   = (const float*)d_in[3];
    const float* in_b   = (const float*)d_in[4];
    const float* in_g   = (const float*)d_in[5];
    const float* in_bb  = (const float*)d_in[6];
    const float* Wq     = (const float*)d_in[7];
    const float* Wk     = (const float*)d_in[8];
    const float* Wv     = (const float*)d_in[9];
    const float* We     = (const float*)d_in[10];
    const float* be     = (const float*)d_in[11];
    const float* Wo     = (const float*)d_in[12];
    const float* bo     = (const float*)d_in[13];
    const float* ln1_g  = (const float*)d_in[14];
    const float* ln1_b  = (const float*)d_in[15];
    const float* ln2_g  = (const float*)d_in[16];
    const float* ln2_b  = (const float*)d_in[17];
    const float* f1_W   = (const float*)d_in[18];
    const float* f1_b   = (const float*)d_in[19];
    const float* f2_W   = (const float*)d_in[20];
    const float* f2_b   = (const float*)d_in[21];
    const float* cls1_W = (const float*)d_in[22];
    const float* cls1_b = (const float*)d_in[23];
    const float* cls2_W = (const float*)d_in[24];
    const float* cls2_b = (const float*)d_in[25];
    float* out = (float*)d_out;

    const int* src = ei;
    const int* dst = ei + NE;

    // ---- workspace layout (~197 MB) ----
    char* w = (char*)d_ws;
    float* B0 = (float*)w;            w += (size_t)NN * H * 4;       // h / out (fp32)
    ushort* hb = (ushort*)w;          w += (size_t)NN * H * 2;       // bf16 activations
    char* pool = w;                   w += (size_t)NN * 1024 * 2;    // 102.4 MB union
    ushort* qkv  = (ushort*)pool;                                    // N x 768 bf16
    ushort* aggb = (ushort*)(pool + (size_t)NN * 768 * 2);           // N x 256 bf16
    float*  tproj = (float*)pool;                                    // input-proj t
    ushort* xb   = (ushort*)(pool + (size_t)NN * H * 4);             // N x 224 bf16
    ushort* tb   = (ushort*)pool;                                    // FFN N x 1024 bf16
    float*  t1   = (float*)pool;                                     // cls hidden fp32
    int* deg    = (int*)w;            w += (size_t)NN * 4;
    int* cursor = (int*)w;            w += (size_t)NN * 4;
    int* rowptr = (int*)w;            w += (size_t)(NN + 2) * 4;
    int* bsum   = (int*)w;            w += 1024;
    int* csr_src = (int*)w;           w += (size_t)NE * 4;
    float2* csr_ea = (float2*)w;      w += (size_t)NE * 8;
    ushort* wqkv_t = (ushort*)w;      w += (size_t)LAYERS * 768 * 256 * 2;
    ushort* wo_t  = (ushort*)w;       w += (size_t)LAYERS * 65536 * 2;
    ushort* f1_t  = (ushort*)w;       w += (size_t)LAYERS * 262144 * 2;
    ushort* f2_t  = (ushort*)w;       w += (size_t)LAYERS * 262144 * 2;
    ushort* c1_t  = (ushort*)w;       w += (size_t)32768 * 2;
    ushort* inw_t = (ushort*)w;       w += (size_t)256 * KIN * 2;

    dim3 blk(256);
    const int ln_grid = (NN + 3) / 4;
    const int e_grid = (NE + 255) / 256;
    const int n_grid = (NN + 255) / 256;
    const int ty = (NN + 127) / 128;

    // ---- CSR build ----
    hipMemsetAsync(deg, 0, (size_t)NN * 4, stream);
    hipMemsetAsync(cursor, 0, (size_t)NN * 4, stream);
    deg_kernel<<<e_grid, blk, 0, stream>>>(dst, deg);
    scan1_kernel<<<n_grid, blk, 0, stream>>>(deg, rowptr, bsum);
    scan2_kernel<<<1, blk, 0, stream>>>(bsum, n_grid);
    scan3_kernel<<<n_grid, blk, 0, stream>>>(rowptr, bsum);
    fill_kernel<<<e_grid, blk, 0, stream>>>(src, dst, ea, rowptr, cursor, csr_src, csr_ea);

    // ---- weight convert/transpose ----
    wtqkv_kernel<<<(int)(((long)LAYERS * 768 * 256 + 255) / 256), blk, 0, stream>>>(Wq, Wk, Wv, wqkv_t);
    wtgen_kernel<<<(int)(((long)LAYERS * 65536 + 255) / 256), blk, 0, stream>>>(Wo, wo_t, LAYERS, 256, 256);
    wtgen_kernel<<<(int)(((long)LAYERS * 262144 + 255) / 256), blk, 0, stream>>>(f1_W, f1_t, LAYERS, 256, 1024);
    wtgen_kernel<<<(int)(((long)LAYERS * 262144 + 255) / 256), blk, 0, stream>>>(f2_W, f2_t, LAYERS, 1024, 256);
    wtgen_kernel<<<(32768 + 255) / 256, blk, 0, stream>>>(cls1_W, c1_t, 1, 256, 128);
    wtin_kernel<<<(256 * KIN + 255) / 256, blk, 0, stream>>>(in_W, inw_t);

    // ---- input projection (MFMA) ----
    xcast_kernel<<<(int)(((long)NN * KIN + 255) / 256), blk, 0, stream>>>(x, xb);
    {
        gemm_bf16_kernel<<<2 * ty, blk, 0, stream>>>(xb, KIN, inw_t, in_b, nullptr, 0,
                                                     tproj, nullptr, H, NN, KIN, 0, 2);
        ln256_kernel<<<ln_grid, blk, 0, stream>>>(tproj, nullptr, nullptr, in_g, in_bb, B0, nullptr, NN, 1);
    }

    for (int l = 0; l < LAYERS; ++l) {
        const float* we  = We + (long)l * 16;
        const float* bel = be + (long)l * 8;
        const float* bol = bo + (long)l * H;
        const float* g1 = ln1_g + (long)l * H;
        const float* b1 = ln1_b + (long)l * H;
        const float* g2 = ln2_g + (long)l * H;
        const float* b2 = ln2_b + (long)l * H;
        const float* bf1 = f1_b + (long)l * FF;
        const float* bf2 = f2_b + (long)l * H;

        // hb = bf16(LN1(h))
        ln256_kernel<<<ln_grid, blk, 0, stream>>>(B0, nullptr, nullptr, g1, b1, nullptr, hb, NN, 0);

        // fused QKV (M=768) + 8-head gather attention
        gemm_bf16_kernel<<<6 * ty, blk, 0, stream>>>(hb, H, wqkv_t + (long)l * 768 * 256,
            nullptr, nullptr, 0, nullptr, qkv, 768, NN, H, 0, 6);
        attn_kernel<<<(NN + 3) / 4, blk, 0, stream>>>(qkv, rowptr, csr_src, csr_ea, we, bel, aggb);

        // B0 = LN(aggb@Wo^T + bo + h); hb = bf16(out)
        gemm_bf16_kernel<<<2 * ty, blk, 0, stream>>>(aggb, H, wo_t + (long)l * 65536,
            bol, nullptr, 0, nullptr, qkv, H, NN, H, 0, 2);   // reuse qkv head as woo
        ln256_kernel<<<ln_grid, blk, 0, stream>>>(nullptr, qkv, B0, g2, b2, B0, hb, NN, 0);

        // FFN one-shot: tb = gelu(hb@f1^T+b) bf16 ; B0 = tb@f2^T + b + B0
        gemm_bf16_kernel<<<8 * ty, blk, 0, stream>>>(hb, H, f1_t + (long)l * 262144,
            bf1, nullptr, 0, nullptr, tb, FF, NN, H, 1, 8);
        gemm_bf16_kernel<<<2 * ty, blk, 0, stream>>>(tb, FF, f2_t + (long)l * 262144,
            bf2, B0, H, B0, (l == LAYERS - 1) ? hb : nullptr, H, NN, FF, 0, 2);
    }

    // ---- classifier ----
    {
        gemm_bf16_kernel<<<1 * ty, blk, 0, stream>>>(hb, H, c1_t, cls1_b, nullptr, 0,
                                                     t1, nullptr, 128, NN, H, 1, 1);
        cls_kernel<<<n_grid, blk, 0, stream>>>(t1, cls2_W, cls2_b, out);
    }
}

// Round 12
// 2911.841 us; speedup vs baseline: 1.0741x; 1.0096x over previous
//
#include <hip/hip_runtime.h>
#include <math.h>

#define NN 50000
#define NE 800000
#define FIN 197
#define KIN 224          // FIN zero-padded to multiple of 32
#define H 256
#define HEADS 8
#define HD 32
#define LAYERS 5
#define FF 1024
#define INV_SCALE 0.17677669529663687f   // 1/sqrt(32)

typedef __attribute__((ext_vector_type(8))) short short8;
typedef __attribute__((ext_vector_type(4))) float f32x4;
typedef unsigned short ushort;

// fast GELU via exp2/rcp (max abs err ~3e-4 vs exact erf form)
__device__ __forceinline__ float gelu_f(float x) {
    float x2 = x * x;
    float u = __builtin_fmaf(0.044715f * x2, x, x);
    float e = __builtin_amdgcn_exp2f(-2.3022075f * u);
    return x * __builtin_amdgcn_rcpf(1.0f + e);
}
__device__ __forceinline__ ushort f2b(float f) {        // fp32 -> bf16 RNE
    unsigned u = __float_as_uint(f);
    u += 0x7fffu + ((u >> 16) & 1u);
    return (ushort)(u >> 16);
}
__device__ __forceinline__ float b2f(ushort b) {
    return __uint_as_float(((unsigned)b) << 16);
}
__device__ __forceinline__ float dot2b(unsigned a, unsigned b) {  // 2 packed bf16 pairs
    float a0 = __uint_as_float(a << 16), a1 = __uint_as_float(a & 0xffff0000u);
    float b0 = __uint_as_float(b << 16), b1 = __uint_as_float(b & 0xffff0000u);
    return a0 * b0 + a1 * b1;
}

// async global->LDS 16B per lane; LDS dest = wave-uniform base + lane*16
__device__ __forceinline__ void load16_lds(const ushort* gp, ushort* lp) {
    __builtin_amdgcn_global_load_lds(
        (const __attribute__((address_space(1))) unsigned int*)gp,
        (__attribute__((address_space(3))) unsigned int*)lp,
        16, 0, 0);
}

// ---------------- MFMA bf16 GEMM: C = act(A @ Bt^T + bias) + res ----------------
// XCD-aware 1-D grid swizzle (round 11, kept: FETCH 100->80MB) + async
// global_load_lds width-16 staging (round-12 change: round-11 counters show
// MfmaUtil 7.8%/VALU 19%/HBM 15%/occ 20% -- staging-latency-bound; the m97
// ladder step for this exact fix was 1.69x). LDS tile is UNPADDED (32-ushort
// = 64B rows) because global_load_lds lands lane i at base+i*16 -- lane i
// covers row i>>2, cols (i&3)*8..+8, which is exactly offset i*16.
__global__ __launch_bounds__(256) void gemm_bf16_kernel(
    const ushort* __restrict__ A, int lda,
    const ushort* __restrict__ Bt,
    const float* __restrict__ bias,
    const float* __restrict__ res, int ldr,
    float* __restrict__ Cf, ushort* __restrict__ Cb, int ldc,
    int n, int K, int act, int gx)
{
    __shared__ ushort As[128 * 32];
    __shared__ ushort Bs[128 * 32];
    int tid = threadIdx.x;
    int lane = tid & 63;
    int wave = tid >> 6;
    int wr = wave >> 1, wc = wave & 1;

    // swizzled block mapping: groups of (8 row-tiles x gx col-tiles)
    int tiles_y = (n + 127) >> 7;
    int lin = blockIdx.x;
    int gsz = gx * 8;
    int group = lin / gsz;
    int rem = lin - group * gsz;
    int rows_left = tiles_y - group * 8;
    int rg = rows_left < 8 ? rows_left : 8;
    int r = rem % rg;
    int c = rem / rg;
    int brow = (group * 8 + r) * 128;
    int bcol = c * 128;

    f32x4 acc[4][4] = {};
    int m0 = lane & 15;
    int koff = (lane >> 4) * 8;

    // per-lane staging coords: row-in-16 = lane>>2, col8 = (lane&3)*8
    int rA = lane >> 2;
    int c8 = (lane & 3) * 8;

    // clamped global row indices for this wave's 2 A-issues (rows wave*32 + p*16 + rA)
    long arow0, arow1, brow0, brow1;
    {
        int gr0 = brow + wave * 32 + rA;        if (gr0 >= n) gr0 = n - 1;
        int gr1 = brow + wave * 32 + 16 + rA;   if (gr1 >= n) gr1 = n - 1;
        arow0 = (long)gr0 * lda;
        arow1 = (long)gr1 * lda;
        brow0 = (long)(bcol + wave * 32 + rA) * K;
        brow1 = (long)(bcol + wave * 32 + 16 + rA) * K;
    }
    ushort* lA0 = &As[(wave * 32) * 32];
    ushort* lA1 = &As[(wave * 32 + 16) * 32];
    ushort* lB0 = &Bs[(wave * 32) * 32];
    ushort* lB1 = &Bs[(wave * 32 + 16) * 32];

    for (int k0 = 0; k0 < K; k0 += 32) {
        load16_lds(A + arow0 + k0 + c8, lA0);
        load16_lds(A + arow1 + k0 + c8, lA1);
        load16_lds(Bt + brow0 + k0 + c8, lB0);
        load16_lds(Bt + brow1 + k0 + c8, lB1);
        __syncthreads();
        short8 af[4], bfr[4];
        #pragma unroll
        for (int i = 0; i < 4; ++i)
            af[i] = *(const short8*)&As[(wr * 64 + i * 16 + m0) * 32 + koff];
        #pragma unroll
        for (int j = 0; j < 4; ++j)
            bfr[j] = *(const short8*)&Bs[(wc * 64 + j * 16 + m0) * 32 + koff];
        #pragma unroll
        for (int i = 0; i < 4; ++i)
            #pragma unroll
            for (int j = 0; j < 4; ++j)
                acc[i][j] = __builtin_amdgcn_mfma_f32_16x16x32_bf16(af[i], bfr[j], acc[i][j], 0, 0, 0);
        __syncthreads();
    }

    int crow0 = (lane >> 4) * 4;
    int ccol = lane & 15;
    #pragma unroll
    for (int i = 0; i < 4; ++i) {
        #pragma unroll
        for (int rr = 0; rr < 4; ++rr) {
            int grow = brow + wr * 64 + i * 16 + crow0 + rr;
            if (grow >= n) continue;
            #pragma unroll
            for (int j = 0; j < 4; ++j) {
                int gcol = bcol + wc * 64 + j * 16 + ccol;
                float v = acc[i][j][rr];
                if (bias) v += bias[gcol];
                if (act) v = gelu_f(v);
                if (res) v += res[(long)grow * ldr + gcol];
                if (Cf) Cf[(long)grow * ldc + gcol] = v;
                if (Cb) Cb[(long)grow * ldc + gcol] = f2b(v);
            }
        }
    }
}

// ---------------- LayerNorm rows of 256; input fp32 (af) or bf16 (ab) ----------------
__global__ __launch_bounds__(256) void ln256_kernel(
    const float* __restrict__ af, const ushort* __restrict__ ab,
    const float* __restrict__ res,
    const float* __restrict__ g, const float* __restrict__ bta,
    float* __restrict__ outf, ushort* __restrict__ outb, int n, int post_gelu)
{
    int row = blockIdx.x * 4 + (threadIdx.x >> 6);
    if (row >= n) return;
    int lane = threadIdx.x & 63;
    float4 v;
    if (af) {
        v = *(const float4*)(af + (long)row * H + lane * 4);
    } else {
        ushort4 vb = *(const ushort4*)(ab + (long)row * H + lane * 4);
        v.x = b2f(vb.x); v.y = b2f(vb.y); v.z = b2f(vb.z); v.w = b2f(vb.w);
    }
    if (res) {
        float4 r = *(const float4*)(res + (long)row * H + lane * 4);
        v.x += r.x; v.y += r.y; v.z += r.z; v.w += r.w;
    }
    float s = v.x + v.y + v.z + v.w;
    #pragma unroll
    for (int off = 1; off < 64; off <<= 1) s += __shfl_xor(s, off);
    float mean = s * (1.0f / H);
    float dx = v.x - mean, dy = v.y - mean, dz = v.z - mean, dw = v.w - mean;
    float qs = dx * dx + dy * dy + dz * dz + dw * dw;
    #pragma unroll
    for (int off = 1; off < 64; off <<= 1) qs += __shfl_xor(qs, off);
    float rstd = rsqrtf(qs * (1.0f / H) + 1e-5f);
    float4 gg = *(const float4*)(g + lane * 4);
    float4 bb = *(const float4*)(bta + lane * 4);
    float4 o;
    o.x = dx * rstd * gg.x + bb.x;
    o.y = dy * rstd * gg.y + bb.y;
    o.z = dz * rstd * gg.z + bb.z;
    o.w = dw * rstd * gg.w + bb.w;
    if (post_gelu) { o.x = gelu_f(o.x); o.y = gelu_f(o.y); o.z = gelu_f(o.z); o.w = gelu_f(o.w); }
    if (outf) *(float4*)(outf + (long)row * H + lane * 4) = o;
    if (outb) {
        ushort4 ob = { f2b(o.x), f2b(o.y), f2b(o.z), f2b(o.w) };
        *(ushort4*)(outb + (long)row * H + lane * 4) = ob;
    }
}

// ---------------- conversions ----------------
__global__ __launch_bounds__(256) void xcast_kernel(const float* __restrict__ x,
                                                    ushort* __restrict__ xb)
{
    long i = (long)blockIdx.x * 256 + threadIdx.x;
    if (i >= (long)NN * KIN) return;
    int n = (int)(i / KIN), c = (int)(i % KIN);
    xb[i] = (c < FIN) ? f2b(x[(long)n * FIN + c]) : (ushort)0;
}

__global__ __launch_bounds__(256) void wtin_kernel(const float* __restrict__ W,
                                                   ushort* __restrict__ Wt)
{
    int i = blockIdx.x * 256 + threadIdx.x;
    if (i >= 256 * KIN) return;
    int m = i / KIN, k = i % KIN;
    Wt[i] = (k < FIN) ? f2b(W[(long)k * H + m]) : (ushort)0;
}

__global__ __launch_bounds__(256) void wtqkv_kernel(
    const float* __restrict__ Wq, const float* __restrict__ Wk,
    const float* __restrict__ Wv, ushort* __restrict__ out)
{
    long i = (long)blockIdx.x * 256 + threadIdx.x;
    if (i >= (long)LAYERS * 768 * 256) return;
    int l = (int)(i / (768 * 256));
    int r = (int)(i % (768 * 256));
    int m = r >> 8, k = r & 255;
    const float* W = (m < 256) ? Wq : ((m < 512) ? Wk : Wv);
    out[i] = f2b(W[(long)l * 65536 + (long)k * 256 + (m & 255)]);
}

__global__ __launch_bounds__(256) void wtgen_kernel(
    const float* __restrict__ W, ushort* __restrict__ out, int L, int K, int M)
{
    long i = (long)blockIdx.x * 256 + threadIdx.x;
    if (i >= (long)L * K * M) return;
    int l = (int)(i / ((long)K * M));
    int r = (int)(i % ((long)K * M));
    int m = r / K, k = r % K;
    out[i] = f2b(W[(long)l * K * M + (long)k * M + m]);
}

// ---------------- CSR build ----------------
__global__ __launch_bounds__(256) void deg_kernel(const int* __restrict__ dst,
                                                   int* __restrict__ deg)
{
    int e = blockIdx.x * 256 + threadIdx.x;
    if (e >= NE) return;
    atomicAdd(&deg[dst[e]], 1);
}

__global__ __launch_bounds__(256) void scan1_kernel(const int* __restrict__ deg,
                                                     int* __restrict__ rowptr,
                                                     int* __restrict__ bsum)
{
    __shared__ int buf[256];
    int tid = threadIdx.x;
    int i = blockIdx.x * 256 + tid;
    int v = (i < NN) ? deg[i] : 0;
    buf[tid] = v;
    __syncthreads();
    #pragma unroll
    for (int off = 1; off < 256; off <<= 1) {
        int t = (tid >= off) ? buf[tid - off] : 0;
        __syncthreads();
        buf[tid] += t;
        __syncthreads();
    }
    if (i < NN) rowptr[i] = buf[tid] - v;
    if (tid == 255) bsum[blockIdx.x] = buf[255];
}

__global__ __launch_bounds__(256) void scan2_kernel(int* __restrict__ bsum, int nb)
{
    __shared__ int buf[256];
    int tid = threadIdx.x;
    int v = (tid < nb) ? bsum[tid] : 0;
    buf[tid] = v;
    __syncthreads();
    #pragma unroll
    for (int off = 1; off < 256; off <<= 1) {
        int t = (tid >= off) ? buf[tid - off] : 0;
        __syncthreads();
        buf[tid] += t;
        __syncthreads();
    }
    if (tid < nb) bsum[tid] = buf[tid] - v;
}

__global__ __launch_bounds__(256) void scan3_kernel(int* __restrict__ rowptr,
                                                     const int* __restrict__ bsum)
{
    int i = blockIdx.x * 256 + threadIdx.x;
    if (i < NN) rowptr[i] += bsum[blockIdx.x];
    if (i == 0) rowptr[NN] = NE;
}

__global__ __launch_bounds__(256) void fill_kernel(
    const int* __restrict__ src, const int* __restrict__ dst,
    const float* __restrict__ ea, const int* __restrict__ rowptr,
    int* __restrict__ cursor, int* __restrict__ csr_src,
    float2* __restrict__ csr_ea)
{
    int e = blockIdx.x * 256 + threadIdx.x;
    if (e >= NE) return;
    int d = dst[e];
    int pos = atomicAdd(&cursor[d], 1);
    int j = rowptr[d] + pos;
    csr_src[j] = src[e];
    csr_ea[j] = *(const float2*)(ea + 2 * e);
}

// ---------------- fused gather attention (one wave per node, all 8 heads) ----------------
__global__ __launch_bounds__(256) void attn_kernel(
    const ushort* __restrict__ qkv,
    const int* __restrict__ rowptr, const int* __restrict__ csr_src,
    const float2* __restrict__ csr_ea,
    const float* __restrict__ We, const float* __restrict__ be,
    ushort* __restrict__ aggb)
{
    int node = blockIdx.x * 4 + (threadIdx.x >> 6);
    if (node >= NN) return;
    int lane = threadIdx.x & 63;
    int h = lane >> 3;                 // global head 0..7
    float w0 = We[h], w1 = We[8 + h], bb = be[h];

    uint2 q2 = *(const uint2*)(qkv + (long)node * 768 + lane * 4);
    int jbeg = rowptr[node], jend = rowptr[node + 1];

    float m = -1e30f, l = 0.f;
    float a0 = 0.f, a1 = 0.f, a2 = 0.f, a3 = 0.f;

    uint2 kN, vN; float2 eaN;
    if (jbeg < jend) {
        int s0 = csr_src[jbeg];
        eaN = csr_ea[jbeg];
        const ushort* kr = qkv + (long)s0 * 768 + 256;
        kN = *(const uint2*)(kr + lane * 4);
        vN = *(const uint2*)(kr + 256 + lane * 4);
    }
    for (int j = jbeg; j < jend; ++j) {
        uint2 k2 = kN, v2 = vN; float2 eab = eaN;
        if (j + 1 < jend) {
            int s1 = csr_src[j + 1];
            eaN = csr_ea[j + 1];
            const ushort* kr = qkv + (long)s1 * 768 + 256;
            kN = *(const uint2*)(kr + lane * 4);
            vN = *(const uint2*)(kr + 256 + lane * 4);
        }
        float p = dot2b(q2.x, k2.x) + dot2b(q2.y, k2.y);
        p += __shfl_xor(p, 1);
        p += __shfl_xor(p, 2);
        p += __shfl_xor(p, 4);         // sum over 8 lanes = 32 channels
        float sc = p * INV_SCALE + eab.x * w0 + eab.y * w1 + bb;
        float vx = __uint_as_float(v2.x << 16);
        float vy = __uint_as_float(v2.x & 0xffff0000u);
        float vz = __uint_as_float(v2.y << 16);
        float vw = __uint_as_float(v2.y & 0xffff0000u);
        float mn = fmaxf(m, sc);
        float scale = __expf(m - mn);
        float e = __expf(sc - mn);
        l = l * scale + e;
        a0 = a0 * scale + e * vx;
        a1 = a1 * scale + e * vy;
        a2 = a2 * scale + e * vz;
        a3 = a3 * scale + e * vw;
        m = mn;
    }
    float inv = 1.0f / (l + 1e-16f);
    ushort4 o = { f2b(a0 * inv), f2b(a1 * inv), f2b(a2 * inv), f2b(a3 * inv) };
    *(ushort4*)(aggb + (long)node * 256 + lane * 4) = o;
}

// ---------------- classifier tail ----------------
__global__ __launch_bounds__(256) void cls_kernel(
    const float* __restrict__ t1, const float* __restrict__ W,
    const float* __restrict__ b, float* __restrict__ out)
{
    int i = blockIdx.x * 256 + threadIdx.x;
    if (i >= NN) return;
    const float* tp = t1 + (long)i * 128;
    float a0 = 0.f, a1 = 0.f;
    #pragma unroll
    for (int j = 0; j < 128; j += 4) {
        float4 t = *(const float4*)(tp + j);
        a0 += t.x * W[(j + 0) * 2] + t.y * W[(j + 1) * 2] + t.z * W[(j + 2) * 2] + t.w * W[(j + 3) * 2];
        a1 += t.x * W[(j + 0) * 2 + 1] + t.y * W[(j + 1) * 2 + 1] + t.z * W[(j + 2) * 2 + 1] + t.w * W[(j + 3) * 2 + 1];
    }
    float l0 = a0 + b[0], l1 = a1 + b[1];
    out[(long)i * 2 + 0] = l0;
    out[(long)i * 2 + 1] = l1;
    float mx = fmaxf(l0, l1);
    float p0 = expf(l0 - mx), p1 = expf(l1 - mx);
    float sden = p0 + p1;
    out[2L * NN + (long)i * 2 + 0] = p0 / sden;
    out[2L * NN + (long)i * 2 + 1] = p1 / sden;
}

extern "C" void kernel_launch(void* const* d_in, const int* in_sizes, int n_in,
                              void* d_out, int out_size, void* d_ws, size_t ws_size,
                              hipStream_t stream) {
    const float* x      = (const float*)d_in[0];
    const int*   ei     = (const int*)d_in[1];
    const float* ea     = (const float*)d_in[2];
    const float* in_W   = (const float*)d_in[3];
    const float* in_b   = (const float*)d_in[4];
    const float* in_g   = (const float*)d_in[5];
    const float* in_bb  = (const float*)d_in[6];
    const float* Wq     = (const float*)d_in[7];
    const float* Wk     = (const float*)d_in[8];
    const float* Wv     = (const float*)d_in[9];
    const float* We     = (const float*)d_in[10];
    const float* be     = (const float*)d_in[11];
    const float* Wo     = (const float*)d_in[12];
    const float* bo     = (const float*)d_in[13];
    const float* ln1_g  = (const float*)d_in[14];
    const float* ln1_b  = (const float*)d_in[15];
    const float* ln2_g  = (const float*)d_in[16];
    const float* ln2_b  = (const float*)d_in[17];
    const float* f1_W   = (const float*)d_in[18];
    const float* f1_b   = (const float*)d_in[19];
    const float* f2_W   = (const float*)d_in[20];
    const float* f2_b   = (const float*)d_in[21];
    const float* cls1_W = (const float*)d_in[22];
    const float* cls1_b = (const float*)d_in[23];
    const float* cls2_W = (const float*)d_in[24];
    const float* cls2_b = (const float*)d_in[25];
    float* out = (float*)d_out;

    const int* src = ei;
    const int* dst = ei + NE;

    // ---- workspace layout (~197 MB) ----
    char* w = (char*)d_ws;
    float* B0 = (float*)w;            w += (size_t)NN * H * 4;       // h / out (fp32)
    ushort* hb = (ushort*)w;          w += (size_t)NN * H * 2;       // bf16 activations
    char* pool = w;                   w += (size_t)NN * 1024 * 2;    // 102.4 MB union
    ushort* qkv  = (ushort*)pool;                                    // N x 768 bf16
    ushort* aggb = (ushort*)(pool + (size_t)NN * 768 * 2);           // N x 256 bf16
    float*  tproj = (float*)pool;                                    // input-proj t
    ushort* xb   = (ushort*)(pool + (size_t)NN * H * 4);             // N x 224 bf16
    ushort* tb   = (ushort*)pool;                                    // FFN N x 1024 bf16
    float*  t1   = (float*)pool;                                     // cls hidden fp32
    int* deg    = (int*)w;            w += (size_t)NN * 4;
    int* cursor = (int*)w;            w += (size_t)NN * 4;
    int* rowptr = (int*)w;            w += (size_t)(NN + 2) * 4;
    int* bsum   = (int*)w;            w += 1024;
    int* csr_src = (int*)w;           w += (size_t)NE * 4;
    float2* csr_ea = (float2*)w;      w += (size_t)NE * 8;
    ushort* wqkv_t = (ushort*)w;      w += (size_t)LAYERS * 768 * 256 * 2;
    ushort* wo_t  = (ushort*)w;       w += (size_t)LAYERS * 65536 * 2;
    ushort* f1_t  = (ushort*)w;       w += (size_t)LAYERS * 262144 * 2;
    ushort* f2_t  = (ushort*)w;       w += (size_t)LAYERS * 262144 * 2;
    ushort* c1_t  = (ushort*)w;       w += (size_t)32768 * 2;
    ushort* inw_t = (ushort*)w;       w += (size_t)256 * KIN * 2;

    dim3 blk(256);
    const int ln_grid = (NN + 3) / 4;
    const int e_grid = (NE + 255) / 256;
    const int n_grid = (NN + 255) / 256;
    const int ty = (NN + 127) / 128;

    // ---- CSR build ----
    hipMemsetAsync(deg, 0, (size_t)NN * 4, stream);
    hipMemsetAsync(cursor, 0, (size_t)NN * 4, stream);
    deg_kernel<<<e_grid, blk, 0, stream>>>(dst, deg);
    scan1_kernel<<<n_grid, blk, 0, stream>>>(deg, rowptr, bsum);
    scan2_kernel<<<1, blk, 0, stream>>>(bsum, n_grid);
    scan3_kernel<<<n_grid, blk, 0, stream>>>(rowptr, bsum);
    fill_kernel<<<e_grid, blk, 0, stream>>>(src, dst, ea, rowptr, cursor, csr_src, csr_ea);

    // ---- weight convert/transpose ----
    wtqkv_kernel<<<(int)(((long)LAYERS * 768 * 256 + 255) / 256), blk, 0, stream>>>(Wq, Wk, Wv, wqkv_t);
    wtgen_kernel<<<(int)(((long)LAYERS * 65536 + 255) / 256), blk, 0, stream>>>(Wo, wo_t, LAYERS, 256, 256);
    wtgen_kernel<<<(int)(((long)LAYERS * 262144 + 255) / 256), blk, 0, stream>>>(f1_W, f1_t, LAYERS, 256, 1024);
    wtgen_kernel<<<(int)(((long)LAYERS * 262144 + 255) / 256), blk, 0, stream>>>(f2_W, f2_t, LAYERS, 1024, 256);
    wtgen_kernel<<<(32768 + 255) / 256, blk, 0, stream>>>(cls1_W, c1_t, 1, 256, 128);
    wtin_kernel<<<(256 * KIN + 255) / 256, blk, 0, stream>>>(in_W, inw_t);

    // ---- input projection (MFMA) ----
    xcast_kernel<<<(int)(((long)NN * KIN + 255) / 256), blk, 0, stream>>>(x, xb);
    {
        gemm_bf16_kernel<<<2 * ty, blk, 0, stream>>>(xb, KIN, inw_t, in_b, nullptr, 0,
                                                     tproj, nullptr, H, NN, KIN, 0, 2);
        ln256_kernel<<<ln_grid, blk, 0, stream>>>(tproj, nullptr, nullptr, in_g, in_bb, B0, nullptr, NN, 1);
    }

    for (int l = 0; l < LAYERS; ++l) {
        const float* we  = We + (long)l * 16;
        const float* bel = be + (long)l * 8;
        const float* bol = bo + (long)l * H;
        const float* g1 = ln1_g + (long)l * H;
        const float* b1 = ln1_b + (long)l * H;
        const float* g2 = ln2_g + (long)l * H;
        const float* b2 = ln2_b + (long)l * H;
        const float* bf1 = f1_b + (long)l * FF;
        const float* bf2 = f2_b + (long)l * H;

        // hb = bf16(LN1(h))
        ln256_kernel<<<ln_grid, blk, 0, stream>>>(B0, nullptr, nullptr, g1, b1, nullptr, hb, NN, 0);

        // fused QKV (M=768) + 8-head gather attention
        gemm_bf16_kernel<<<6 * ty, blk, 0, stream>>>(hb, H, wqkv_t + (long)l * 768 * 256,
            nullptr, nullptr, 0, nullptr, qkv, 768, NN, H, 0, 6);
        attn_kernel<<<(NN + 3) / 4, blk, 0, stream>>>(qkv, rowptr, csr_src, csr_ea, we, bel, aggb);

        // B0 = LN(aggb@Wo^T + bo + h); hb = bf16(out)
        gemm_bf16_kernel<<<2 * ty, blk, 0, stream>>>(aggb, H, wo_t + (long)l * 65536,
            bol, nullptr, 0, nullptr, qkv, H, NN, H, 0, 2);   // reuse qkv head as woo
        ln256_kernel<<<ln_grid, blk, 0, stream>>>(nullptr, qkv, B0, g2, b2, B0, hb, NN, 0);

        // FFN one-shot: tb = gelu(hb@f1^T+b) bf16 ; B0 = tb@f2^T + b + B0
        gemm_bf16_kernel<<<8 * ty, blk, 0, stream>>>(hb, H, f1_t + (long)l * 262144,
            bf1, nullptr, 0, nullptr, tb, FF, NN, H, 1, 8);
        gemm_bf16_kernel<<<2 * ty, blk, 0, stream>>>(tb, FF, f2_t + (long)l * 262144,
            bf2, B0, H, B0, (l == LAYERS - 1) ? hb : nullptr, H, NN, FF, 0, 2);
    }

    // ---- classifier ----
    {
        gemm_bf16_kernel<<<1 * ty, blk, 0, stream>>>(hb, H, c1_t, cls1_b, nullptr, 0,
                                                     t1, nullptr, 128, NN, H, 1, 1);
        cls_kernel<<<n_grid, blk, 0, stream>>>(t1, cls2_W, cls2_b, out);
    }
}